// Round 5
// baseline (1667.007 us; speedup 1.0000x reference)
//
#include <hip/hip_runtime.h>
#include <stdint.h>

#define B_ 128
#define T_ 1024
#define BT_ (B_*T_)
#define H_ 64
#define G_ 192
#define PL_ 432
#define NP_ 5
#define FUSED_ 288
#define N_IN 41
#define NSTATIC 128
#define NRECUR 256
#define NGEMM 2048

typedef unsigned short u16;
typedef __attribute__((ext_vector_type(8))) short bf16x8;
typedef __attribute__((ext_vector_type(4))) float f32x4;
typedef _Float16 h2 __attribute__((ext_vector_type(2)));
typedef _Float16 h8 __attribute__((ext_vector_type(8)));

__device__ inline float bf2f(u16 u){ union{float f; unsigned int i;} c; c.i = ((unsigned int)u)<<16; return c.f; }
__device__ inline u16 f2bf(float f){ unsigned int u = __float_as_uint(f); unsigned int r = (u + 0x7fffu + ((u>>16)&1u))>>16; return (u16)r; }
__device__ inline _Float16 bf2h(u16 u){ return (_Float16)bf2f(u); }
__device__ inline float sigm(float x){ return 1.f/(1.f+__expf(-x)); }
__device__ inline float tanh_(float x){ float t = __expf(fminf(fmaxf(2.f*x,-30.f),30.f)); return (t-1.f)/(t+1.f); }
__device__ inline float gelu_(float x){ return 0.5f*x*(1.f + erff(x*0.70710678118654752f)); }
__device__ inline float wredsum(float v){
  #pragma unroll
  for(int o=32;o>0;o>>=1) v += __shfl_xor(v,o);
  return v;
}

#if __has_builtin(__builtin_amdgcn_fdot2)
__device__ inline float dot2(h2 a, h2 b, float c){ return __builtin_amdgcn_fdot2(a, b, c, false); }
#else
__device__ inline float dot2(h2 a, h2 b, float c){ return c + (float)a.x*(float)b.x + (float)a.y*(float)b.y; }
#endif

// ---------------- input canonicalization + flag zeroing ----------------
struct CvtArgs {
  const void* src[N_IN];
  unsigned dstOff[N_IN];
  unsigned cnt[N_IN];
  unsigned blkStart[N_IN+1];
};

__global__ __launch_bounds__(256) void convert_k(CvtArgs a, u16* __restrict__ dst,
                                                 unsigned* __restrict__ flags){
  int b = blockIdx.x;
  // tail blocks: zero the 4096 producer-consumer flags (graph-replay safe)
  if ((unsigned)b >= a.blkStart[N_IN]){
    unsigned base = ((unsigned)b - a.blkStart[N_IN])*2048u;
    #pragma unroll
    for(int e=0;e<8;e++){ unsigned idx = base + e*256u + threadIdx.x; if (idx < 4096u) flags[idx] = 0u; }
    return;
  }
  const bool isbf = (((const u16*)a.src[21])[0] == 0x3F80u);
  int lo = 0, hi = N_IN;
  while (hi - lo > 1){ int mid = (lo+hi)>>1; if (a.blkStart[mid] <= (unsigned)b) lo = mid; else hi = mid; }
  const int i = lo;
  const unsigned lb = (unsigned)b - a.blkStart[i];
  const unsigned n = a.cnt[i];
  u16* d = dst + a.dstOff[i];
  if (isbf){
    const u16* s = (const u16*)a.src[i];
    #pragma unroll
    for(int e=0;e<8;e++){ unsigned idx = lb*2048u + e*256u + threadIdx.x; if (idx < n) d[idx] = s[idx]; }
  } else {
    const float* s = (const float*)a.src[i];
    #pragma unroll
    for(int e=0;e<8;e++){ unsigned idx = lb*2048u + e*256u + threadIdx.x; if (idx < n) d[idx] = f2bf(s[idx]); }
  }
}

// ---------------- GRU recurrence body (R13-exact loop + chunk-flag waits) ----------------
// One wave per chain. Runs in a 64-thread block under waves_per_eu(1,1):
// full 512-VGPR budget (R4 lesson: 256-thr merged kernel got VGPR=72 ->
// weights shelved to AGPR -> +37%/step). Acquire-spin on flags before
// issuing chunks whose t-tile the producer waves may not have written.
template<int LAYER>
__device__ void recur_body(int chain, const u16* gi,
    const u16* __restrict__ WhF, const u16* __restrict__ WhB,
    const u16* __restrict__ bhF, const u16* __restrict__ bhB,
    u16* __restrict__ y_x1, float* __restrict__ hfin,
    const unsigned* flags)
{
  const int dir = chain >> 7;
  const int b = chain & 127;
  const int j = threadIdx.x;           // 0..63
  const u16* Wh = dir ? WhB : WhF;
  const u16* bh = dir ? bhB : bhF;

  h2 wr[32], wz[32], wn[32];
  #pragma unroll
  for(int k8=0;k8<8;k8++){
    uint4 q;
    q = *(const uint4*)(Wh + (size_t)j*64 + k8*8);
    wr[4*k8+0] = (h2){bf2h((u16)(q.x&0xffffu)), bf2h((u16)(q.x>>16))};
    wr[4*k8+1] = (h2){bf2h((u16)(q.y&0xffffu)), bf2h((u16)(q.y>>16))};
    wr[4*k8+2] = (h2){bf2h((u16)(q.z&0xffffu)), bf2h((u16)(q.z>>16))};
    wr[4*k8+3] = (h2){bf2h((u16)(q.w&0xffffu)), bf2h((u16)(q.w>>16))};
    q = *(const uint4*)(Wh + (size_t)(64+j)*64 + k8*8);
    wz[4*k8+0] = (h2){bf2h((u16)(q.x&0xffffu)), bf2h((u16)(q.x>>16))};
    wz[4*k8+1] = (h2){bf2h((u16)(q.y&0xffffu)), bf2h((u16)(q.y>>16))};
    wz[4*k8+2] = (h2){bf2h((u16)(q.z&0xffffu)), bf2h((u16)(q.z>>16))};
    wz[4*k8+3] = (h2){bf2h((u16)(q.w&0xffffu)), bf2h((u16)(q.w>>16))};
    q = *(const uint4*)(Wh + (size_t)(128+j)*64 + k8*8);
    wn[4*k8+0] = (h2){bf2h((u16)(q.x&0xffffu)), bf2h((u16)(q.x>>16))};
    wn[4*k8+1] = (h2){bf2h((u16)(q.y&0xffffu)), bf2h((u16)(q.y>>16))};
    wn[4*k8+2] = (h2){bf2h((u16)(q.z&0xffffu)), bf2h((u16)(q.z>>16))};
    wn[4*k8+3] = (h2){bf2h((u16)(q.w&0xffffu)), bf2h((u16)(q.w>>16))};
  }
  const float bhr = bf2f(bh[j]), bhz = bf2f(bh[64+j]), bhn = bf2f(bh[128+j]);

  __shared__ __align__(16) u16 giLds[2][3072];   // 2 x 16 steps x 192 u16
  __shared__ _Float16 hSf[64];
  h8* hS8 = (h8*)hSf;
  hSf[j] = (_Float16)0.f;              // in-order DS: visible to the loop's reads

  const u16* giC = gi + (size_t)chain * T_ * G_;

  auto issue_chunk = [&](int c, int buf){
    int tbase = dir ? (1008 - c*16) : (c*16);
    const u16* src = giC + (size_t)tbase*G_ + j*8;
    u16* dst = &giLds[buf][0];
    #pragma unroll
    for(int i=0;i<6;i++){
      __builtin_amdgcn_global_load_lds(
        (const __attribute__((address_space(1))) void*)(src + i*512),
        (__attribute__((address_space(3))) void*)(dst + i*512), 16, 0, 0);
    }
  };

  int readyTile = -1;
  auto wait_tile = [&](int c){
    int tbase = dir ? (1008 - c*16) : (c*16);
    int tile = tbase >> 6;
    if (tile == readyTile) return;
    const unsigned* f = &flags[b*16 + tile];
    while (__hip_atomic_load(f, __ATOMIC_ACQUIRE, __HIP_MEMORY_SCOPE_AGENT) == 0u)
      __builtin_amdgcn_s_sleep(2);
    readyTile = tile;
  };

  wait_tile(0);
  issue_chunk(0, 0);

  float h = 0.f;
  for(int c=0; c<64; ++c){
    if (c < 63) wait_tile(c+1);        // spin overlaps in-flight chunk-c DMA
    asm volatile("s_waitcnt vmcnt(0)" ::: "memory");  // chunk c landed in LDS
    if (c < 63) issue_chunk(c+1, (c+1)&1);
    const u16* gbuf = &giLds[c&1][0];
    #pragma unroll 2
    for(int ls=0; ls<16; ++ls){
      int row = dir ? (15-ls) : ls;
      const u16* rowp = gbuf + row*G_;
      float r0=bhr, r1=0.f, z0=bhz, z1=0.f, n0=bhn, n1=0.f;
      #pragma unroll
      for(int k=0;k<8;k++){
        h8 hv = hS8[k];
        h2 p0 = __builtin_shufflevector(hv, hv, 0, 1);
        h2 p1 = __builtin_shufflevector(hv, hv, 2, 3);
        h2 p2 = __builtin_shufflevector(hv, hv, 4, 5);
        h2 p3 = __builtin_shufflevector(hv, hv, 6, 7);
        r0 = dot2(wr[4*k+0], p0, r0); r1 = dot2(wr[4*k+1], p1, r1);
        r0 = dot2(wr[4*k+2], p2, r0); r1 = dot2(wr[4*k+3], p3, r1);
        z0 = dot2(wz[4*k+0], p0, z0); z1 = dot2(wz[4*k+1], p1, z1);
        z0 = dot2(wz[4*k+2], p2, z0); z1 = dot2(wz[4*k+3], p3, z1);
        n0 = dot2(wn[4*k+0], p0, n0); n1 = dot2(wn[4*k+1], p1, n1);
        n0 = dot2(wn[4*k+2], p2, n0); n1 = dot2(wn[4*k+3], p3, n1);
      }
      float gr = bf2f(rowp[j]), gz = bf2f(rowp[64+j]), gn = bf2f(rowp[128+j]);

      float r  = sigm(gr + (r0+r1));
      float z  = sigm(gz + (z0+z1));
      float nn = tanh_(gn + r*(n0+n1));
      h = (1.f - z)*nn + z*h;

      hSf[j] = (_Float16)h;            // in-order DS; next iter's reads see it

      if (LAYER == 0){
        int s = c*16 + ls;
        int t = dir ? (T_-1-s) : s;
        y_x1[((size_t)b*T_ + t)*128 + dir*64 + j] = f2bf(h);
      }
    }
  }
  if (LAYER == 1) hfin[b*FUSED_ + dir*64 + j] = h;
}

// tslot -> physical tile, ordered {0,15,1,14,...}: first 256 producer blocks
// (b fastest) cover every chain's first-needed tile (fwd t=0, bwd t=1023).
__device__ inline int tile_order(int tslot){ return (tslot & 1) ? (15 - (tslot >> 1)) : (tslot >> 1); }

__device__ inline void publish_flag(unsigned* flags, int idx){
  __threadfence();                      // drain this wave's stores to agent scope
  if (threadIdx.x == 0)
    __hip_atomic_store(&flags[idx], 1u, __ATOMIC_RELEASE, __HIP_MEMORY_SCOPE_AGENT);
}

// ---------------- fused L1: gi_gemm0 (K=32, raw A) producers + recur layer 0 ----------------
// ALL blocks are ONE WAVE. waves_per_eu(1,1): 4 single-wave blocks/CU ->
// recur wave gets a private SIMD + full VGPR budget; producer waves backfill
// the other 3 SIMDs. No circular waits in any placement -> deadlock-free.
__global__ __launch_bounds__(64)
__attribute__((amdgpu_waves_per_eu(1,1)))
void fused0_k(
    const void* __restrict__ Araw,
    const u16* __restrict__ Wf, const u16* __restrict__ Wb,
    const u16* __restrict__ biasF, const u16* __restrict__ biasB,
    u16* gi,
    const u16* __restrict__ WhF, const u16* __restrict__ WhB,
    const u16* __restrict__ bhF, const u16* __restrict__ bhB,
    u16* __restrict__ y_x1, unsigned* flags, const u16* __restrict__ detect)
{
  if (blockIdx.x < NRECUR){
    recur_body<0>(blockIdx.x, gi, WhF, WhB, bhF, bhB, y_x1, nullptr, flags);
    return;
  }
  const bool isbf = (detect[0] == 0x3F80u);
  const int g = blockIdx.x - NRECUR;
  const int bb = g & 127;
  const int ttile = tile_order(g >> 7);
  const int lane = threadIdx.x;
  const int l15 = lane & 15, quad = lane >> 4;

  #pragma unroll
  for(int m0=0;m0<4;m0++){
    const size_t mBase = ((size_t)bb*16 + ttile)*64 + m0*16;
    bf16x8 afr;
    if (isbf){
      afr = *(const bf16x8*)((const u16*)Araw + (mBase + l15)*32 + quad*8);
    } else {
      const float* af = (const float*)Araw + (mBase + l15)*32 + quad*8;
      float4 f0 = *(const float4*)af;
      float4 f1 = *(const float4*)(af+4);
      union { bf16x8 v; u16 e[8]; } u_;
      u_.e[0]=f2bf(f0.x); u_.e[1]=f2bf(f0.y); u_.e[2]=f2bf(f0.z); u_.e[3]=f2bf(f0.w);
      u_.e[4]=f2bf(f1.x); u_.e[5]=f2bf(f1.y); u_.e[6]=f2bf(f1.z); u_.e[7]=f2bf(f1.w);
      afr = u_.v;
    }
    #pragma unroll
    for(int half=0; half<2; ++half){
      const u16* W    = half ? Wb : Wf;
      const u16* bias = half ? biasB : biasF;
      u16* o = gi + (size_t)half * BT_ * G_;
      for(int nt=0; nt<12; ++nt){
        int n = nt*16 + l15;
        f32x4 acc = {0.f,0.f,0.f,0.f};
        bf16x8 bfr = *(const bf16x8*)(W + n*32 + quad*8);
        acc = __builtin_amdgcn_mfma_f32_16x16x32_bf16(bfr, afr, acc, 0,0,0);
        ushort4 bb4 = *(const ushort4*)(bias + nt*16 + quad*4);
        ushort4 pk;
        pk.x = f2bf(acc[0] + bf2f(bb4.x));
        pk.y = f2bf(acc[1] + bf2f(bb4.y));
        pk.z = f2bf(acc[2] + bf2f(bb4.z));
        pk.w = f2bf(acc[3] + bf2f(bb4.w));
        *(ushort4*)(o + (mBase + l15)*G_ + nt*16 + quad*4) = pk;
      }
    }
  }
  publish_flag(flags, bb*16 + ttile);
}

// ---------------- conv helper (64-thread version: 2 lanes per output chan) ----------------
template<int KS, int DIL, int PAD>
__device__ inline void do_conv64(const float* pS, const u16* Wc, const u16* bc,
                                 float* fused, int b, int o, int p, int cslot)
{
  const int Lout = PL_ + 2*PAD - DIL*(KS-1);
  float w[5][KS];
  #pragma unroll
  for(int i=0;i<5;i++)
    #pragma unroll
    for(int t=0;t<KS;t++) w[i][t] = bf2f(Wc[(o*5+i)*KS + t]);
  float bias = bf2f(bc[o]);
  float acc = 0.f;
  for(int l=p; l<Lout; l+=2){
    float s = bias;
    #pragma unroll
    for(int t=0;t<KS;t++){
      int idx = l - PAD + t*DIL;
      if (idx >= 0 && idx < PL_){
        #pragma unroll
        for(int i=0;i<5;i++) s += w[i][t]*pS[i*PL_ + idx];
      }
    }
    acc += gelu_(s);
  }
  acc += __shfl_xor(acc, 32);
  if (p == 0) fused[b*FUSED_ + 192 + cslot*32 + o] = acc/(float)Lout;
}

// ---------------- fused static branch, 64-thread single-wave version ----------------
// ao kept in registers (each lane owns l = tid, tid+64, ... -> 7 pos x 5 heads);
// S3b and S4 merged; pS overwrites q rows at the lane's own l (race-free).
__device__ void static_body(int b, int tid,
   const u16* sx, const u16* smW, const u16* smb,
   const u16* lng, const u16* lnb, const u16* gW, const u16* gb,
   const void* physRaw, const u16* aW, const u16* ab,
   const u16* oW, const u16* ob,
   const u16* W1c, const u16* b1c, const u16* W2c, const u16* b2c,
   const u16* W3c, const u16* b3c,
   float* fused, bool isbf)
{
  __shared__ float qS[15*PL_];          // 25.9 KB; rows 0..4 reused as pS
  __shared__ float gS[5];
  __shared__ float kmS[5], knS[5];

  // S1: static embed (gelu+LN) + gates
  {
    int j = tid;
    float acc = bf2f(smb[j]);
    #pragma unroll
    for(int k=0;k<16;k++) acc += bf2f(sx[b*16+k])*bf2f(smW[j*16+k]);
    float xg = gelu_(acc);
    float m = wredsum(xg)*(1.f/64.f);
    float d = xg - m;
    float v = wredsum(d*d)*(1.f/64.f);
    float se = d*rsqrtf(v+1e-5f)*bf2f(lng[j]) + bf2f(lnb[j]);
    fused[b*FUSED_ + 128 + j] = se;
    #pragma unroll
    for(int i=0;i<5;i++){
      float p = se*bf2f(gW[i*64+j]);
      float s = wredsum(p);
      if (j == 0) gS[i] = sigm(s + bf2f(gb[i]));
    }
  }
  __syncthreads();

  // S2: qkv into LDS (phys read raw, dtype branch)
  for(int l=tid; l<PL_; l+=64){
    float pv[5];
    #pragma unroll
    for(int i=0;i<5;i++){
      size_t idx = ((size_t)b*5+i)*PL_ + l;
      float pr = isbf ? bf2f(((const u16*)physRaw)[idx]) : ((const float*)physRaw)[idx];
      pv[i] = pr * gS[i];
    }
    #pragma unroll
    for(int c=0;c<15;c++){
      float a = bf2f(ab[c]);
      #pragma unroll
      for(int i=0;i<5;i++) a += pv[i]*bf2f(aW[c*5+i]);
      qS[c*PL_ + l] = a;
    }
  }
  __syncthreads();

  // S3a: per-head k max/min (single-wave reduce)
  {
    float mx[5], mn[5];
    #pragma unroll
    for(int h=0;h<5;h++){ mx[h]=-1e30f; mn[h]=1e30f; }
    for(int jj=tid; jj<PL_; jj+=64){
      #pragma unroll
      for(int h=0;h<5;h++){ float kv=qS[(5+h)*PL_+jj]; mx[h]=fmaxf(mx[h],kv); mn[h]=fminf(mn[h],kv); }
    }
    #pragma unroll
    for(int o=32;o>0;o>>=1){
      #pragma unroll
      for(int h=0;h<5;h++){ mx[h]=fmaxf(mx[h],__shfl_xor(mx[h],o)); mn[h]=fminf(mn[h],__shfl_xor(mn[h],o)); }
    }
    if (tid < 5){ kmS[tid]=mx[tid]; knS[tid]=mn[tid]; }
  }
  __syncthreads();

  // S3b + S4 merged: attention per (l, head) in registers, project, write pS
  for(int l=tid; l<PL_; l+=64){
    float qv[5], aov[5];
    #pragma unroll
    for(int h=0;h<5;h++) qv[h] = qS[h*PL_+l];
    #pragma unroll
    for(int h=0;h<5;h++){
      float s = qv[h];
      float m = fmaxf(s*kmS[h], s*knS[h]);
      const float* kR = &qS[(5+h)*PL_];
      const float* vR = &qS[(10+h)*PL_];
      float den=0.f, num=0.f;
      #pragma unroll 4
      for(int j2=0;j2<PL_;j2++){
        float e = __expf(s*kR[j2]-m);
        den += e; num += e*vR[j2];
      }
      aov[h] = num/den;
    }
    #pragma unroll
    for(int c=0;c<5;c++){
      float s = bf2f(ob[c]);
      #pragma unroll
      for(int hh=0;hh<5;hh++) s += aov[hh]*bf2f(oW[c*5+hh]);
      qS[c*PL_ + l] = s;     // overwrite own l of q rows only: race-free
    }
  }
  __syncthreads();

  // S5: dilated convs + mean -> fused[192..287]
  int o = tid & 31, p = tid >> 5;
  do_conv64<3,1,1>(qS, W1c, b1c, fused, b, o, p, 0);
  do_conv64<5,2,2>(qS, W2c, b2c, fused, b, o, p, 1);
  do_conv64<9,4,4>(qS, W3c, b3c, fused, b, o, p, 2);
}

// ---------------- fused L2: gemm128 producers + static branch + recur layer 1 ----------------
__global__ __launch_bounds__(64)
__attribute__((amdgpu_waves_per_eu(1,1)))
void fused1_k(
    const u16* __restrict__ A,
    const u16* __restrict__ Wf, const u16* __restrict__ Wb,
    const u16* __restrict__ biasF, const u16* __restrict__ biasB,
    u16* gi,
    const u16* __restrict__ WhF, const u16* __restrict__ WhB,
    const u16* __restrict__ bhF, const u16* __restrict__ bhB,
    float* __restrict__ fusedOut, unsigned* flags,
    const u16* __restrict__ sx, const u16* __restrict__ smW, const u16* __restrict__ smb,
    const u16* __restrict__ lng, const u16* __restrict__ lnb,
    const u16* __restrict__ gW, const u16* __restrict__ gb,
    const void* __restrict__ physRaw, const u16* __restrict__ aW, const u16* __restrict__ ab,
    const u16* __restrict__ oW, const u16* __restrict__ ob,
    const u16* __restrict__ W1c, const u16* __restrict__ b1c,
    const u16* __restrict__ W2c, const u16* __restrict__ b2c,
    const u16* __restrict__ W3c, const u16* __restrict__ b3c,
    const u16* __restrict__ detect)
{
  const bool isbf = (detect[0] == 0x3F80u);
  if (blockIdx.x < NRECUR){
    recur_body<1>(blockIdx.x, gi, WhF, WhB, bhF, bhB, nullptr, fusedOut, flags);
    return;
  }
  if (blockIdx.x >= NRECUR + NGEMM){
    static_body(blockIdx.x - (NRECUR + NGEMM), threadIdx.x,
                sx, smW, smb, lng, lnb, gW, gb, physRaw, aW, ab,
                oW, ob, W1c, b1c, W2c, b2c, W3c, b3c, fusedOut, isbf);
    return;
  }
  const int g = blockIdx.x - NRECUR;
  const int bb = g & 127;
  const int ttile = tile_order(g >> 7);
  const int lane = threadIdx.x;
  const int l15 = lane & 15, quad = lane >> 4;

  #pragma unroll
  for(int m0=0;m0<4;m0++){
    const size_t mBase = ((size_t)bb*16 + ttile)*64 + m0*16;
    bf16x8 afr[4];
    #pragma unroll
    for(int kc=0;kc<4;kc++)
      afr[kc] = *(const bf16x8*)(A + (mBase + l15)*128 + kc*32 + quad*8);
    #pragma unroll
    for(int half=0; half<2; ++half){
      const u16* W    = half ? Wb : Wf;
      const u16* bias = half ? biasB : biasF;
      u16* o = gi + (size_t)half * BT_ * G_;
      for(int nt=0; nt<12; ++nt){
        int n = nt*16 + l15;
        f32x4 acc = {0.f,0.f,0.f,0.f};
        #pragma unroll
        for(int kc=0;kc<4;kc++){
          bf16x8 bfr = *(const bf16x8*)(W + n*128 + kc*32 + quad*8);
          acc = __builtin_amdgcn_mfma_f32_16x16x32_bf16(bfr, afr[kc], acc, 0,0,0);
        }
        ushort4 bb4 = *(const ushort4*)(bias + nt*16 + quad*4);
        ushort4 pk;
        pk.x = f2bf(acc[0] + bf2f(bb4.x));
        pk.y = f2bf(acc[1] + bf2f(bb4.y));
        pk.z = f2bf(acc[2] + bf2f(bb4.z));
        pk.w = f2bf(acc[3] + bf2f(bb4.w));
        *(ushort4*)(o + (mBase + l15)*G_ + nt*16 + quad*4) = pk;
      }
    }
  }
  publish_flag(flags, bb*16 + ttile);
}

// ---------------- head: LN + MLP (output dtype adaptive) ----------------
__global__ __launch_bounds__(448) void head_k(const float* __restrict__ fused,
   const u16* __restrict__ lng, const u16* __restrict__ lnb,
   const u16* __restrict__ W1, const u16* __restrict__ b1,
   const u16* __restrict__ W2, const u16* __restrict__ b2,
   void* __restrict__ out, const u16* __restrict__ detect)
{
  const bool isbf = (detect[0] == 0x3F80u);
  int b = blockIdx.x, tid = threadIdx.x;
  __shared__ float fS[FUSED_];
  __shared__ float hS[128];
  __shared__ float red[32];
  float v = (tid < FUSED_) ? fused[b*FUSED_ + tid] : 0.f;
  float s1 = wredsum(v);
  float s2 = wredsum(v*v);
  int wv = tid>>6;
  if ((tid&63)==0){ red[wv]=s1; red[8+wv]=s2; }
  __syncthreads();
  if (tid==0){
    float S=0.f, SS=0.f;
    for(int i=0;i<7;i++){ S+=red[i]; SS+=red[8+i]; }
    float m = S/288.f;
    red[16]=m; red[17]=SS/288.f - m*m;
  }
  __syncthreads();
  float m = red[16], var = red[17];
  if (tid < FUSED_) fS[tid] = (v-m)*rsqrtf(var+1e-5f)*bf2f(lng[tid]) + bf2f(lnb[tid]);
  __syncthreads();
  if (tid < 128){
    float a = bf2f(b1[tid]);
    const u16* wr = W1 + (size_t)tid*FUSED_;
    #pragma unroll
    for(int k8=0;k8<36;k8++){
      uint4 q = *(const uint4*)(wr + k8*8);
      a += fS[8*k8+0]*bf2f((u16)(q.x&0xffffu)) + fS[8*k8+1]*bf2f((u16)(q.x>>16))
         + fS[8*k8+2]*bf2f((u16)(q.y&0xffffu)) + fS[8*k8+3]*bf2f((u16)(q.y>>16))
         + fS[8*k8+4]*bf2f((u16)(q.z&0xffffu)) + fS[8*k8+5]*bf2f((u16)(q.z>>16))
         + fS[8*k8+6]*bf2f((u16)(q.w&0xffffu)) + fS[8*k8+7]*bf2f((u16)(q.w>>16));
    }
    hS[tid] = gelu_(a);
  }
  __syncthreads();
  if (tid < PL_){
    float a = bf2f(b2[tid]);
    const u16* wr = W2 + (size_t)tid*128;
    #pragma unroll
    for(int k8=0;k8<16;k8++){
      uint4 q = *(const uint4*)(wr + k8*8);
      a += hS[8*k8+0]*bf2f((u16)(q.x&0xffffu)) + hS[8*k8+1]*bf2f((u16)(q.x>>16))
         + hS[8*k8+2]*bf2f((u16)(q.y&0xffffu)) + hS[8*k8+3]*bf2f((u16)(q.y>>16))
         + hS[8*k8+4]*bf2f((u16)(q.z&0xffffu)) + hS[8*k8+5]*bf2f((u16)(q.z>>16))
         + hS[8*k8+6]*bf2f((u16)(q.w&0xffffu)) + hS[8*k8+7]*bf2f((u16)(q.w>>16));
    }
    size_t oi = (size_t)b*PL_ + tid;
    if (isbf) ((u16*)out)[oi] = f2bf(a);
    else      ((float*)out)[oi] = a;
  }
}

extern "C" void kernel_launch(void* const* d_in, const int* in_sizes, int n_in,
                              void* d_out, int out_size, void* d_ws, size_t ws_size,
                              hipStream_t stream)
{
  static const unsigned cnts[N_IN] = {
    4194304, 2048, 276480,
    6144, 12288, 192, 192,
    6144, 12288, 192, 192,
    24576, 12288, 192, 192,
    24576, 12288, 192, 192,
    1024, 64, 64, 64,
    320, 5,
    75, 15,
    25, 5,
    480, 32, 800, 32, 1440, 32,
    288, 288,
    36864, 128, 55296, 432
  };

  char* ws = (char*)d_ws;
  size_t off = 0;
  auto alloc = [&](size_t bytes){ size_t o = off; off = (off + bytes + 255) & ~(size_t)255; return o; };

  CvtArgs ca;
  const u16* cin[N_IN];
  unsigned totalBlocks = 0;
  for (int i=0;i<N_IN;i++){
    ca.src[i] = d_in[i];
    ca.cnt[i] = cnts[i];
    size_t o = alloc((size_t)cnts[i]*2);
    ca.dstOff[i] = (unsigned)(o/2);
    cin[i] = (const u16*)(ws + o);
    ca.blkStart[i] = totalBlocks;
    // inputs 0 (omni_seq) and 2 (phys) are consumed raw by fused0/static_body
    if (i != 0 && i != 2) totalBlocks += (cnts[i] + 2047u)/2048u;
  }
  ca.blkStart[N_IN] = totalBlocks;
  u16* canon = (u16*)ws;

  u16*   gi    = (u16*)  (ws + alloc((size_t)2*BT_*G_*2));
  u16*   x1    = (u16*)  (ws + alloc((size_t)BT_*128*2));
  float* fused = (float*)(ws + alloc((size_t)B_*FUSED_*4));
  unsigned* flags = (unsigned*)(ws + alloc((size_t)4096*4));
  (void)ws_size; (void)in_sizes; (void)n_in; (void)out_size;

  // convert weights + zero both flag arrays (2 tail blocks)
  convert_k<<<totalBlocks + 2, 256, 0, stream>>>(ca, canon, flags);

  fused0_k<<<NRECUR + NGEMM, 64, 0, stream>>>(d_in[0],
      cin[3], cin[7], cin[5], cin[9], gi,
      cin[4], cin[8], cin[6], cin[10], x1, flags, (const u16*)d_in[21]);

  fused1_k<<<NRECUR + NGEMM + NSTATIC, 64, 0, stream>>>(x1,
      cin[11], cin[15], cin[13], cin[17], gi,
      cin[12], cin[16], cin[14], cin[18], fused, flags + 2048,
      cin[1], cin[19], cin[20], cin[21], cin[22], cin[23], cin[24],
      d_in[2], cin[25], cin[26],
      cin[27], cin[28], cin[29], cin[30], cin[31], cin[32], cin[33], cin[34],
      (const u16*)d_in[21]);

  head_k<<<128, 448, 0, stream>>>(fused, cin[35], cin[36], cin[37], cin[38], cin[39], cin[40],
                                  d_out, (const u16*)d_in[21]);
}

// Round 6
// 1215.795 us; speedup vs baseline: 1.3711x; 1.3711x over previous
//
#include <hip/hip_runtime.h>
#include <stdint.h>

#define B_ 128
#define T_ 1024
#define BT_ (B_*T_)
#define H_ 64
#define G_ 192
#define PL_ 432
#define NP_ 5
#define FUSED_ 288
#define N_IN 41
#define NSTATIC 128

typedef unsigned short u16;
typedef __attribute__((ext_vector_type(8))) short bf16x8;
typedef __attribute__((ext_vector_type(4))) float f32x4;
typedef _Float16 h2 __attribute__((ext_vector_type(2)));
typedef _Float16 h8 __attribute__((ext_vector_type(8)));

__device__ inline float bf2f(u16 u){ union{float f; unsigned int i;} c; c.i = ((unsigned int)u)<<16; return c.f; }
__device__ inline u16 f2bf(float f){ unsigned int u = __float_as_uint(f); unsigned int r = (u + 0x7fffu + ((u>>16)&1u))>>16; return (u16)r; }
__device__ inline _Float16 bf2h(u16 u){ return (_Float16)bf2f(u); }
__device__ inline u16 f2h_bits(float f){ union{_Float16 h; u16 u;} c; c.h = (_Float16)f; return c.u; }
__device__ inline float sigm(float x){ return 1.f/(1.f+__expf(-x)); }
__device__ inline float tanh_(float x){ float t = __expf(fminf(fmaxf(2.f*x,-30.f),30.f)); return (t-1.f)/(t+1.f); }
__device__ inline float gelu_(float x){ return 0.5f*x*(1.f + erff(x*0.70710678118654752f)); }
__device__ inline float wredsum(float v){
  #pragma unroll
  for(int o=32;o>0;o>>=1) v += __shfl_xor(v,o);
  return v;
}

#if __has_builtin(__builtin_amdgcn_fdot2)
__device__ inline float dot2(h2 a, h2 b, float c){ return __builtin_amdgcn_fdot2(a, b, c, false); }
#else
__device__ inline float dot2(h2 a, h2 b, float c){ return c + (float)a.x*(float)b.x + (float)a.y*(float)b.y; }
#endif

// ---------------- input canonicalization ----------------
// input 0 (omni_seq) -> f16 canon (consumed by recur0's in-loop gi dots);
// input 2 (phys) read raw by static_body; everything else -> bf16 canon.
struct CvtArgs {
  const void* src[N_IN];
  unsigned dstOff[N_IN];
  unsigned cnt[N_IN];
  unsigned blkStart[N_IN+1];
};

__global__ __launch_bounds__(256) void convert_k(CvtArgs a, u16* __restrict__ dst){
  const bool isbf = (((const u16*)a.src[21])[0] == 0x3F80u);
  int b = blockIdx.x;
  int lo = 0, hi = N_IN;
  while (hi - lo > 1){ int mid = (lo+hi)>>1; if (a.blkStart[mid] <= (unsigned)b) lo = mid; else hi = mid; }
  const int i = lo;
  const unsigned lb = (unsigned)b - a.blkStart[i];
  const unsigned n = a.cnt[i];
  u16* d = dst + a.dstOff[i];
  if (i == 0){
    // omni_seq -> f16
    if (isbf){
      const u16* s = (const u16*)a.src[i];
      #pragma unroll
      for(int e=0;e<8;e++){ unsigned idx = lb*2048u + e*256u + threadIdx.x; if (idx < n) d[idx] = f2h_bits(bf2f(s[idx])); }
    } else {
      const float* s = (const float*)a.src[i];
      #pragma unroll
      for(int e=0;e<8;e++){ unsigned idx = lb*2048u + e*256u + threadIdx.x; if (idx < n) d[idx] = f2h_bits(s[idx]); }
    }
    return;
  }
  if (isbf){
    const u16* s = (const u16*)a.src[i];
    #pragma unroll
    for(int e=0;e<8;e++){ unsigned idx = lb*2048u + e*256u + threadIdx.x; if (idx < n) d[idx] = s[idx]; }
  } else {
    const float* s = (const float*)a.src[i];
    #pragma unroll
    for(int e=0;e<8;e++){ unsigned idx = lb*2048u + e*256u + threadIdx.x; if (idx < n) d[idx] = f2bf(s[idx]); }
  }
}

// ---------------- layer-0 recurrence with IN-LOOP gi (gi_gemm0 eliminated) ----------------
// R13-exact skeleton (1 wave/chain, 256 blocks = 256 CUs, waves_per_eu(1,1)).
// NEW: gi_r/z/n computed in-loop from the f16 x-row via 48 extra dot2/step —
// issued into the ~85% idle slots of the latency-bound step. Removes the
// gi_gemm0 launch + 200MB of gi write+read traffic. Lane j holds Wih rows
// {j,64+j,128+j} (48 h2 regs) on top of Whh's 96. x staged via 1KB chunk DMA.
__global__ __launch_bounds__(64)
__attribute__((amdgpu_waves_per_eu(1,1)))
void recur0_k(const u16* __restrict__ x16,
    const u16* __restrict__ WiF, const u16* __restrict__ WiB,
    const u16* __restrict__ biF, const u16* __restrict__ biB,
    const u16* __restrict__ WhF, const u16* __restrict__ WhB,
    const u16* __restrict__ bhF, const u16* __restrict__ bhB,
    u16* __restrict__ y_x1)
{
  const int chain = blockIdx.x;
  const int dir = chain >> 7;
  const int b = chain & 127;
  const int j = threadIdx.x;           // lane 0..63
  const u16* Wh = dir ? WhB : WhF;
  const u16* Wi = dir ? WiB : WiF;
  const u16* bh = dir ? bhB : bhF;
  const u16* bi = dir ? biB : biF;

  // Whh rows j, 64+j, 128+j as packed f16 pairs (bf16->f16 exact)
  h2 wr[32], wz[32], wn[32];
  #pragma unroll
  for(int k8=0;k8<8;k8++){
    uint4 q;
    q = *(const uint4*)(Wh + (size_t)j*64 + k8*8);
    wr[4*k8+0] = (h2){bf2h((u16)(q.x&0xffffu)), bf2h((u16)(q.x>>16))};
    wr[4*k8+1] = (h2){bf2h((u16)(q.y&0xffffu)), bf2h((u16)(q.y>>16))};
    wr[4*k8+2] = (h2){bf2h((u16)(q.z&0xffffu)), bf2h((u16)(q.z>>16))};
    wr[4*k8+3] = (h2){bf2h((u16)(q.w&0xffffu)), bf2h((u16)(q.w>>16))};
    q = *(const uint4*)(Wh + (size_t)(64+j)*64 + k8*8);
    wz[4*k8+0] = (h2){bf2h((u16)(q.x&0xffffu)), bf2h((u16)(q.x>>16))};
    wz[4*k8+1] = (h2){bf2h((u16)(q.y&0xffffu)), bf2h((u16)(q.y>>16))};
    wz[4*k8+2] = (h2){bf2h((u16)(q.z&0xffffu)), bf2h((u16)(q.z>>16))};
    wz[4*k8+3] = (h2){bf2h((u16)(q.w&0xffffu)), bf2h((u16)(q.w>>16))};
    q = *(const uint4*)(Wh + (size_t)(128+j)*64 + k8*8);
    wn[4*k8+0] = (h2){bf2h((u16)(q.x&0xffffu)), bf2h((u16)(q.x>>16))};
    wn[4*k8+1] = (h2){bf2h((u16)(q.y&0xffffu)), bf2h((u16)(q.y>>16))};
    wn[4*k8+2] = (h2){bf2h((u16)(q.z&0xffffu)), bf2h((u16)(q.z>>16))};
    wn[4*k8+3] = (h2){bf2h((u16)(q.w&0xffffu)), bf2h((u16)(q.w>>16))};
  }
  // Wih rows j, 64+j, 128+j (32 wide)
  h2 ur[16], uz[16], un[16];
  #pragma unroll
  for(int k4=0;k4<4;k4++){
    uint4 q;
    q = *(const uint4*)(Wi + (size_t)j*32 + k4*8);
    ur[4*k4+0] = (h2){bf2h((u16)(q.x&0xffffu)), bf2h((u16)(q.x>>16))};
    ur[4*k4+1] = (h2){bf2h((u16)(q.y&0xffffu)), bf2h((u16)(q.y>>16))};
    ur[4*k4+2] = (h2){bf2h((u16)(q.z&0xffffu)), bf2h((u16)(q.z>>16))};
    ur[4*k4+3] = (h2){bf2h((u16)(q.w&0xffffu)), bf2h((u16)(q.w>>16))};
    q = *(const uint4*)(Wi + (size_t)(64+j)*32 + k4*8);
    uz[4*k4+0] = (h2){bf2h((u16)(q.x&0xffffu)), bf2h((u16)(q.x>>16))};
    uz[4*k4+1] = (h2){bf2h((u16)(q.y&0xffffu)), bf2h((u16)(q.y>>16))};
    uz[4*k4+2] = (h2){bf2h((u16)(q.z&0xffffu)), bf2h((u16)(q.z>>16))};
    uz[4*k4+3] = (h2){bf2h((u16)(q.w&0xffffu)), bf2h((u16)(q.w>>16))};
    q = *(const uint4*)(Wi + (size_t)(128+j)*32 + k4*8);
    un[4*k4+0] = (h2){bf2h((u16)(q.x&0xffffu)), bf2h((u16)(q.x>>16))};
    un[4*k4+1] = (h2){bf2h((u16)(q.y&0xffffu)), bf2h((u16)(q.y>>16))};
    un[4*k4+2] = (h2){bf2h((u16)(q.z&0xffffu)), bf2h((u16)(q.z>>16))};
    un[4*k4+3] = (h2){bf2h((u16)(q.w&0xffffu)), bf2h((u16)(q.w>>16))};
  }
  // r/z share accumulators across x-dots and h-dots (biases folded);
  // n kept split: nx (gi_n, init bih_n) vs nh (gh_n, init bhh_n).
  const float bR  = bf2f(bh[j])     + bf2f(bi[j]);
  const float bZ  = bf2f(bh[64+j])  + bf2f(bi[64+j]);
  const float bhn = bf2f(bh[128+j]);
  const float bin = bf2f(bi[128+j]);

  __shared__ __align__(16) u16 xLds[2][512];     // 2 x 16 steps x 32 f16
  __shared__ _Float16 hSf[64];
  h8* hS8 = (h8*)hSf;
  hSf[j] = (_Float16)0.f;              // in-order DS: visible to the loop's reads

  const u16* xC = x16 + (size_t)b * T_ * 32;

  auto issue_chunk = [&](int c, int buf){
    int tbase = dir ? (1008 - c*16) : (c*16);
    const u16* src = xC + (size_t)tbase*32 + j*8;
    u16* dst = &xLds[buf][0];
    __builtin_amdgcn_global_load_lds(
      (const __attribute__((address_space(1))) void*)src,
      (__attribute__((address_space(3))) void*)dst, 16, 0, 0);
  };

  issue_chunk(0, 0);

  float h = 0.f;
  for(int c=0; c<64; ++c){
    asm volatile("s_waitcnt vmcnt(0)" ::: "memory");  // chunk c landed in LDS
    if (c < 63) issue_chunk(c+1, (c+1)&1);
    const u16* xbuf = &xLds[c&1][0];
    #pragma unroll 2
    for(int ls=0; ls<16; ++ls){
      int row = dir ? (15-ls) : ls;
      const h8* x8 = (const h8*)(xbuf + row*32);
      float r0=bR, r1=0.f, z0=bZ, z1=0.f;
      float nh0=bhn, nh1=0.f, nx0=bin, nx1=0.f;
      // x-dots: gi_r/z/n (48 dot2, broadcast LDS reads)
      #pragma unroll
      for(int k=0;k<4;k++){
        h8 xv = x8[k];
        h2 q0 = __builtin_shufflevector(xv, xv, 0, 1);
        h2 q1 = __builtin_shufflevector(xv, xv, 2, 3);
        h2 q2 = __builtin_shufflevector(xv, xv, 4, 5);
        h2 q3 = __builtin_shufflevector(xv, xv, 6, 7);
        r0 = dot2(ur[4*k+0], q0, r0); r1 = dot2(ur[4*k+1], q1, r1);
        r0 = dot2(ur[4*k+2], q2, r0); r1 = dot2(ur[4*k+3], q3, r1);
        z0 = dot2(uz[4*k+0], q0, z0); z1 = dot2(uz[4*k+1], q1, z1);
        z0 = dot2(uz[4*k+2], q2, z0); z1 = dot2(uz[4*k+3], q3, z1);
        nx0 = dot2(un[4*k+0], q0, nx0); nx1 = dot2(un[4*k+1], q1, nx1);
        nx0 = dot2(un[4*k+2], q2, nx0); nx1 = dot2(un[4*k+3], q3, nx1);
      }
      // h-dots: gh_r/z/n (96 dot2)
      #pragma unroll
      for(int k=0;k<8;k++){
        h8 hv = hS8[k];
        h2 p0 = __builtin_shufflevector(hv, hv, 0, 1);
        h2 p1 = __builtin_shufflevector(hv, hv, 2, 3);
        h2 p2 = __builtin_shufflevector(hv, hv, 4, 5);
        h2 p3 = __builtin_shufflevector(hv, hv, 6, 7);
        r0 = dot2(wr[4*k+0], p0, r0); r1 = dot2(wr[4*k+1], p1, r1);
        r0 = dot2(wr[4*k+2], p2, r0); r1 = dot2(wr[4*k+3], p3, r1);
        z0 = dot2(wz[4*k+0], p0, z0); z1 = dot2(wz[4*k+1], p1, z1);
        z0 = dot2(wz[4*k+2], p2, z0); z1 = dot2(wz[4*k+3], p3, z1);
        nh0 = dot2(wn[4*k+0], p0, nh0); nh1 = dot2(wn[4*k+1], p1, nh1);
        nh0 = dot2(wn[4*k+2], p2, nh0); nh1 = dot2(wn[4*k+3], p3, nh1);
      }
      float r  = sigm(r0+r1);
      float z  = sigm(z0+z1);
      float nn = tanh_((nx0+nx1) + r*(nh0+nh1));
      h = (1.f - z)*nn + z*h;

      hSf[j] = (_Float16)h;            // in-order DS; next iter's reads see it

      int s = c*16 + ls;
      int t = dir ? (T_-1-s) : s;
      y_x1[((size_t)b*T_ + t)*128 + dir*64 + j] = f2bf(h);
    }
  }
}

// ---------------- GRU recurrence layer 1 (R13-exact, reads precomputed gi) ----------------
__global__ __launch_bounds__(64)
__attribute__((amdgpu_waves_per_eu(1,1)))
void recur(const u16* __restrict__ gi,
    const u16* __restrict__ WhF, const u16* __restrict__ WhB,
    const u16* __restrict__ bhF, const u16* __restrict__ bhB,
    float* __restrict__ hfin)
{
  const int chain = blockIdx.x;
  const int dir = chain >> 7;
  const int b = chain & 127;
  const int j = threadIdx.x;           // lane 0..63
  const u16* Wh = dir ? WhB : WhF;
  const u16* bh = dir ? bhB : bhF;

  h2 wr[32], wz[32], wn[32];
  #pragma unroll
  for(int k8=0;k8<8;k8++){
    uint4 q;
    q = *(const uint4*)(Wh + (size_t)j*64 + k8*8);
    wr[4*k8+0] = (h2){bf2h((u16)(q.x&0xffffu)), bf2h((u16)(q.x>>16))};
    wr[4*k8+1] = (h2){bf2h((u16)(q.y&0xffffu)), bf2h((u16)(q.y>>16))};
    wr[4*k8+2] = (h2){bf2h((u16)(q.z&0xffffu)), bf2h((u16)(q.z>>16))};
    wr[4*k8+3] = (h2){bf2h((u16)(q.w&0xffffu)), bf2h((u16)(q.w>>16))};
    q = *(const uint4*)(Wh + (size_t)(64+j)*64 + k8*8);
    wz[4*k8+0] = (h2){bf2h((u16)(q.x&0xffffu)), bf2h((u16)(q.x>>16))};
    wz[4*k8+1] = (h2){bf2h((u16)(q.y&0xffffu)), bf2h((u16)(q.y>>16))};
    wz[4*k8+2] = (h2){bf2h((u16)(q.z&0xffffu)), bf2h((u16)(q.z>>16))};
    wz[4*k8+3] = (h2){bf2h((u16)(q.w&0xffffu)), bf2h((u16)(q.w>>16))};
    q = *(const uint4*)(Wh + (size_t)(128+j)*64 + k8*8);
    wn[4*k8+0] = (h2){bf2h((u16)(q.x&0xffffu)), bf2h((u16)(q.x>>16))};
    wn[4*k8+1] = (h2){bf2h((u16)(q.y&0xffffu)), bf2h((u16)(q.y>>16))};
    wn[4*k8+2] = (h2){bf2h((u16)(q.z&0xffffu)), bf2h((u16)(q.z>>16))};
    wn[4*k8+3] = (h2){bf2h((u16)(q.w&0xffffu)), bf2h((u16)(q.w>>16))};
  }
  const float bhr = bf2f(bh[j]), bhz = bf2f(bh[64+j]), bhn = bf2f(bh[128+j]);

  __shared__ __align__(16) u16 giLds[2][3072];   // 2 x 16 steps x 192 u16
  __shared__ _Float16 hSf[64];
  h8* hS8 = (h8*)hSf;
  hSf[j] = (_Float16)0.f;              // in-order DS: visible to the loop's reads

  const u16* giC = gi + (size_t)chain * T_ * G_;

  auto issue_chunk = [&](int c, int buf){
    int tbase = dir ? (1008 - c*16) : (c*16);
    const u16* src = giC + (size_t)tbase*G_ + j*8;
    u16* dst = &giLds[buf][0];
    #pragma unroll
    for(int i=0;i<6;i++){
      __builtin_amdgcn_global_load_lds(
        (const __attribute__((address_space(1))) void*)(src + i*512),
        (__attribute__((address_space(3))) void*)(dst + i*512), 16, 0, 0);
    }
  };

  issue_chunk(0, 0);

  float h = 0.f;
  for(int c=0; c<64; ++c){
    asm volatile("s_waitcnt vmcnt(0)" ::: "memory");  // chunk c landed in LDS
    if (c < 63) issue_chunk(c+1, (c+1)&1);
    const u16* gbuf = &giLds[c&1][0];
    #pragma unroll 2
    for(int ls=0; ls<16; ++ls){
      int row = dir ? (15-ls) : ls;
      const u16* rowp = gbuf + row*G_;
      float r0=bhr, r1=0.f, z0=bhz, z1=0.f, n0=bhn, n1=0.f;
      #pragma unroll
      for(int k=0;k<8;k++){
        h8 hv = hS8[k];
        h2 p0 = __builtin_shufflevector(hv, hv, 0, 1);
        h2 p1 = __builtin_shufflevector(hv, hv, 2, 3);
        h2 p2 = __builtin_shufflevector(hv, hv, 4, 5);
        h2 p3 = __builtin_shufflevector(hv, hv, 6, 7);
        r0 = dot2(wr[4*k+0], p0, r0); r1 = dot2(wr[4*k+1], p1, r1);
        r0 = dot2(wr[4*k+2], p2, r0); r1 = dot2(wr[4*k+3], p3, r1);
        z0 = dot2(wz[4*k+0], p0, z0); z1 = dot2(wz[4*k+1], p1, z1);
        z0 = dot2(wz[4*k+2], p2, z0); z1 = dot2(wz[4*k+3], p3, z1);
        n0 = dot2(wn[4*k+0], p0, n0); n1 = dot2(wn[4*k+1], p1, n1);
        n0 = dot2(wn[4*k+2], p2, n0); n1 = dot2(wn[4*k+3], p3, n1);
      }
      float gr = bf2f(rowp[j]), gz = bf2f(rowp[64+j]), gn = bf2f(rowp[128+j]);

      float r  = sigm(gr + (r0+r1));
      float z  = sigm(gz + (z0+z1));
      float nn = tanh_(gn + r*(n0+n1));
      h = (1.f - z)*nn + z*h;

      hSf[j] = (_Float16)h;            // in-order DS; next iter's reads see it
    }
  }
  hfin[b*FUSED_ + dir*64 + j] = h;
}

// ---------------- conv helper ----------------
template<int KS, int DIL, int PAD>
__device__ inline void do_conv(const float* pS, const u16* Wc, const u16* bc,
                               float* fused, int b, int o, int p, int cslot)
{
  const int Lout = PL_ + 2*PAD - DIL*(KS-1);
  float w[5][KS];
  #pragma unroll
  for(int i=0;i<5;i++)
    #pragma unroll
    for(int t=0;t<KS;t++) w[i][t] = bf2f(Wc[(o*5+i)*KS + t]);
  float bias = bf2f(bc[o]);
  float acc = 0.f;
  for(int l=p; l<Lout; l+=8){
    float s = bias;
    #pragma unroll
    for(int t=0;t<KS;t++){
      int idx = l - PAD + t*DIL;
      if (idx >= 0 && idx < PL_){
        #pragma unroll
        for(int i=0;i<5;i++) s += w[i][t]*pS[i*PL_ + idx];
      }
    }
    acc += gelu_(s);
  }
  #pragma unroll
  for(int off=1;off<8;off<<=1) acc += __shfl_xor(acc,off);
  if (p == 0) fused[b*FUSED_ + 192 + cslot*32 + o] = acc/(float)Lout;
}

// ---------------- fused static branch (one 256-thr block per batch, all LDS) ----------------
__device__ void static_body(int b, int tid,
   const u16* sx, const u16* smW, const u16* smb,
   const u16* lng, const u16* lnb, const u16* gW, const u16* gb,
   const void* physRaw, const u16* aW, const u16* ab,
   const u16* oW, const u16* ob,
   const u16* W1c, const u16* b1c, const u16* W2c, const u16* b2c,
   const u16* W3c, const u16* b3c,
   float* fused, bool isbf)
{
  __shared__ float qS[15*PL_];          // 25.9 KB; rows 0..4 reused as pS in S4
  __shared__ float aoS[PL_*5];          // 8.6 KB
  __shared__ float gS[5];
  __shared__ float redS[40];
  __shared__ float kmS[5], knS[5];

  if (tid < 64){
    int j = tid;
    float acc = bf2f(smb[j]);
    #pragma unroll
    for(int k=0;k<16;k++) acc += bf2f(sx[b*16+k])*bf2f(smW[j*16+k]);
    float xg = gelu_(acc);
    float m = wredsum(xg)*(1.f/64.f);
    float d = xg - m;
    float v = wredsum(d*d)*(1.f/64.f);
    float se = d*rsqrtf(v+1e-5f)*bf2f(lng[j]) + bf2f(lnb[j]);
    fused[b*FUSED_ + 128 + j] = se;
    #pragma unroll
    for(int i=0;i<5;i++){
      float p = se*bf2f(gW[i*64+j]);
      float s = wredsum(p);
      if (j == 0) gS[i] = sigm(s + bf2f(gb[i]));
    }
  }
  __syncthreads();

  for(int l=tid; l<PL_; l+=256){
    float pv[5];
    #pragma unroll
    for(int i=0;i<5;i++){
      size_t idx = ((size_t)b*5+i)*PL_ + l;
      float pr = isbf ? bf2f(((const u16*)physRaw)[idx]) : ((const float*)physRaw)[idx];
      pv[i] = pr * gS[i];
    }
    #pragma unroll
    for(int c=0;c<15;c++){
      float a = bf2f(ab[c]);
      #pragma unroll
      for(int i=0;i<5;i++) a += pv[i]*bf2f(aW[c*5+i]);
      qS[c*PL_ + l] = a;
    }
  }
  __syncthreads();

  float mx[5], mn[5];
  #pragma unroll
  for(int h=0;h<5;h++){ mx[h]=-1e30f; mn[h]=1e30f; }
  for(int jj=tid; jj<PL_; jj+=256){
    #pragma unroll
    for(int h=0;h<5;h++){ float kv=qS[(5+h)*PL_+jj]; mx[h]=fmaxf(mx[h],kv); mn[h]=fminf(mn[h],kv); }
  }
  #pragma unroll
  for(int o=32;o>0;o>>=1){
    #pragma unroll
    for(int h=0;h<5;h++){ mx[h]=fmaxf(mx[h],__shfl_xor(mx[h],o)); mn[h]=fminf(mn[h],__shfl_xor(mn[h],o)); }
  }
  int wv = tid>>6;
  if ((tid&63)==0){
    #pragma unroll
    for(int h=0;h<5;h++){ redS[wv*10+h]=mx[h]; redS[wv*10+5+h]=mn[h]; }
  }
  __syncthreads();
  if (tid < 5){
    float a=redS[tid], c=redS[5+tid];
    for(int w2=1;w2<4;w2++){ a=fmaxf(a,redS[w2*10+tid]); c=fminf(c,redS[w2*10+5+tid]); }
    kmS[tid]=a; knS[tid]=c;
  }
  __syncthreads();

  for(int i=tid; i<PL_; i+=256){
    #pragma unroll
    for(int h=0;h<5;h++){
      float s = qS[h*PL_+i];
      float m = fmaxf(s*kmS[h], s*knS[h]);
      const float* kR = &qS[(5+h)*PL_];
      const float* vR = &qS[(10+h)*PL_];
      float den=0.f, num=0.f;
      #pragma unroll 4
      for(int j2=0;j2<PL_;j2++){
        float e = __expf(s*kR[j2]-m);
        den += e; num += e*vR[j2];
      }
      aoS[i*5+h] = num/den;
    }
  }
  __syncthreads();

  float* pS = qS;
  for(int l=tid; l<PL_; l+=256){
    float a[5];
    #pragma unroll
    for(int hh=0;hh<5;hh++) a[hh] = aoS[l*5+hh];
    #pragma unroll
    for(int c=0;c<5;c++){
      float s = bf2f(ob[c]);
      #pragma unroll
      for(int hh=0;hh<5;hh++) s += a[hh]*bf2f(oW[c*5+hh]);
      pS[c*PL_ + l] = s;
    }
  }
  __syncthreads();

  int o = tid >> 3, p = tid & 7;
  do_conv<3,1,1>(pS, W1c, b1c, fused, b, o, p, 0);
  do_conv<5,2,2>(pS, W2c, b2c, fused, b, o, p, 1);
  do_conv<9,4,4>(pS, W3c, b3c, fused, b, o, p, 2);
}

// ---------------- merged: layer-1 gi GEMM (K=128) + static branch overlap ----------------
// Static blocks FIRST (blockIdx < NSTATIC) so they dispatch early and run
// concurrently with the 2048 gemm blocks -> static branch time fully hidden.
__global__ __launch_bounds__(256) void gemm128_static_k(const u16* __restrict__ A,
    const u16* __restrict__ Wf, const u16* __restrict__ Wb,
    const u16* __restrict__ biasF, const u16* __restrict__ biasB,
    u16* __restrict__ out,
    const u16* __restrict__ sx, const u16* __restrict__ smW, const u16* __restrict__ smb,
    const u16* __restrict__ lng, const u16* __restrict__ lnb,
    const u16* __restrict__ gW, const u16* __restrict__ gb,
    const void* __restrict__ physRaw, const u16* __restrict__ aW, const u16* __restrict__ ab,
    const u16* __restrict__ oW, const u16* __restrict__ ob,
    const u16* __restrict__ W1c, const u16* __restrict__ b1c,
    const u16* __restrict__ W2c, const u16* __restrict__ b2c,
    const u16* __restrict__ W3c, const u16* __restrict__ b3c,
    float* __restrict__ fused, const u16* __restrict__ detect)
{
  const bool isbf = (detect[0] == 0x3F80u);
  if (blockIdx.x < NSTATIC){
    static_body(blockIdx.x, threadIdx.x, sx, smW, smb, lng, lnb, gW, gb,
                physRaw, aW, ab, oW, ob, W1c, b1c, W2c, b2c, W3c, b3c,
                fused, isbf);
    return;
  }
  const int bid = blockIdx.x - NSTATIC;
  const int wv = threadIdx.x >> 6, lane = threadIdx.x & 63;
  const int l15 = lane & 15, quad = lane >> 4;
  const size_t mBase = (size_t)bid*64 + wv*16;

  bf16x8 afr[4];
  #pragma unroll
  for(int kc=0;kc<4;kc++)
    afr[kc] = *(const bf16x8*)(A + (mBase + l15)*128 + kc*32 + quad*8);

  #pragma unroll
  for(int half=0; half<2; ++half){
    const u16* W    = half ? Wb : Wf;
    const u16* bias = half ? biasB : biasF;
    u16* o = out + (size_t)half * BT_ * G_;
    for(int nt=0; nt<12; ++nt){
      int n = nt*16 + l15;
      f32x4 acc = {0.f,0.f,0.f,0.f};
      #pragma unroll
      for(int kc=0;kc<4;kc++){
        bf16x8 bfr = *(const bf16x8*)(W + n*128 + kc*32 + quad*8);
        acc = __builtin_amdgcn_mfma_f32_16x16x32_bf16(bfr, afr[kc], acc, 0,0,0);
      }
      ushort4 bb = *(const ushort4*)(bias + nt*16 + quad*4);
      ushort4 pk;
      pk.x = f2bf(acc[0] + bf2f(bb.x));
      pk.y = f2bf(acc[1] + bf2f(bb.y));
      pk.z = f2bf(acc[2] + bf2f(bb.z));
      pk.w = f2bf(acc[3] + bf2f(bb.w));
      *(ushort4*)(o + (mBase + l15)*G_ + nt*16 + quad*4) = pk;
    }
  }
}

// ---------------- head: LN + MLP (output dtype adaptive) ----------------
__global__ __launch_bounds__(448) void head_k(const float* __restrict__ fused,
   const u16* __restrict__ lng, const u16* __restrict__ lnb,
   const u16* __restrict__ W1, const u16* __restrict__ b1,
   const u16* __restrict__ W2, const u16* __restrict__ b2,
   void* __restrict__ out, const u16* __restrict__ detect)
{
  const bool isbf = (detect[0] == 0x3F80u);
  int b = blockIdx.x, tid = threadIdx.x;
  __shared__ float fS[FUSED_];
  __shared__ float hS[128];
  __shared__ float red[32];
  float v = (tid < FUSED_) ? fused[b*FUSED_ + tid] : 0.f;
  float s1 = wredsum(v);
  float s2 = wredsum(v*v);
  int wv = tid>>6;
  if ((tid&63)==0){ red[wv]=s1; red[8+wv]=s2; }
  __syncthreads();
  if (tid==0){
    float S=0.f, SS=0.f;
    for(int i=0;i<7;i++){ S+=red[i]; SS+=red[8+i]; }
    float m = S/288.f;
    red[16]=m; red[17]=SS/288.f - m*m;
  }
  __syncthreads();
  float m = red[16], var = red[17];
  if (tid < FUSED_) fS[tid] = (v-m)*rsqrtf(var+1e-5f)*bf2f(lng[tid]) + bf2f(lnb[tid]);
  __syncthreads();
  if (tid < 128){
    float a = bf2f(b1[tid]);
    const u16* wr = W1 + (size_t)tid*FUSED_;
    #pragma unroll
    for(int k8=0;k8<36;k8++){
      uint4 q = *(const uint4*)(wr + k8*8);
      a += fS[8*k8+0]*bf2f((u16)(q.x&0xffffu)) + fS[8*k8+1]*bf2f((u16)(q.x>>16))
         + fS[8*k8+2]*bf2f((u16)(q.y&0xffffu)) + fS[8*k8+3]*bf2f((u16)(q.y>>16))
         + fS[8*k8+4]*bf2f((u16)(q.z&0xffffu)) + fS[8*k8+5]*bf2f((u16)(q.z>>16))
         + fS[8*k8+6]*bf2f((u16)(q.w&0xffffu)) + fS[8*k8+7]*bf2f((u16)(q.w>>16));
    }
    hS[tid] = gelu_(a);
  }
  __syncthreads();
  if (tid < PL_){
    float a = bf2f(b2[tid]);
    const u16* wr = W2 + (size_t)tid*128;
    #pragma unroll
    for(int k8=0;k8<16;k8++){
      uint4 q = *(const uint4*)(wr + k8*8);
      a += hS[8*k8+0]*bf2f((u16)(q.x&0xffffu)) + hS[8*k8+1]*bf2f((u16)(q.x>>16))
         + hS[8*k8+2]*bf2f((u16)(q.y&0xffffu)) + hS[8*k8+3]*bf2f((u16)(q.y>>16))
         + hS[8*k8+4]*bf2f((u16)(q.z&0xffffu)) + hS[8*k8+5]*bf2f((u16)(q.z>>16))
         + hS[8*k8+6]*bf2f((u16)(q.w&0xffffu)) + hS[8*k8+7]*bf2f((u16)(q.w>>16));
    }
    size_t oi = (size_t)b*PL_ + tid;
    if (isbf) ((u16*)out)[oi] = f2bf(a);
    else      ((float*)out)[oi] = a;
  }
}

extern "C" void kernel_launch(void* const* d_in, const int* in_sizes, int n_in,
                              void* d_out, int out_size, void* d_ws, size_t ws_size,
                              hipStream_t stream)
{
  static const unsigned cnts[N_IN] = {
    4194304, 2048, 276480,
    6144, 12288, 192, 192,
    6144, 12288, 192, 192,
    24576, 12288, 192, 192,
    24576, 12288, 192, 192,
    1024, 64, 64, 64,
    320, 5,
    75, 15,
    25, 5,
    480, 32, 800, 32, 1440, 32,
    288, 288,
    36864, 128, 55296, 432
  };

  char* ws = (char*)d_ws;
  size_t off = 0;
  auto alloc = [&](size_t bytes){ size_t o = off; off = (off + bytes + 255) & ~(size_t)255; return o; };

  CvtArgs ca;
  const u16* cin[N_IN];
  unsigned totalBlocks = 0;
  for (int i=0;i<N_IN;i++){
    ca.src[i] = d_in[i];
    ca.cnt[i] = cnts[i];
    size_t o = alloc((size_t)cnts[i]*2);
    ca.dstOff[i] = (unsigned)(o/2);
    cin[i] = (const u16*)(ws + o);
    ca.blkStart[i] = totalBlocks;
    // input 0 canonicalized to f16 (recur0 consumes it); input 2 read raw
    if (i != 2) totalBlocks += (cnts[i] + 2047u)/2048u;
  }
  ca.blkStart[N_IN] = totalBlocks;
  u16* canon = (u16*)ws;

  u16*   gi    = (u16*)  (ws + alloc((size_t)2*BT_*G_*2));
  u16*   x1    = (u16*)  (ws + alloc((size_t)BT_*128*2));
  float* fused = (float*)(ws + alloc((size_t)B_*FUSED_*4));
  (void)ws_size; (void)in_sizes; (void)n_in; (void)out_size;

  convert_k<<<totalBlocks, 256, 0, stream>>>(ca, canon);

  recur0_k<<<256, 64, 0, stream>>>(cin[0], cin[3], cin[7], cin[5], cin[9],
                                   cin[4], cin[8], cin[6], cin[10], x1);

  gemm128_static_k<<<BT_/64 + NSTATIC, 256, 0, stream>>>(x1,
      cin[11], cin[15], cin[13], cin[17], gi,
      cin[1], cin[19], cin[20], cin[21], cin[22], cin[23], cin[24],
      d_in[2], cin[25], cin[26],
      cin[27], cin[28], cin[29], cin[30], cin[31], cin[32], cin[33], cin[34],
      fused, (const u16*)d_in[21]);

  recur<<<256, 64, 0, stream>>>(gi, cin[12], cin[16], cin[14], cin[18], fused);

  head_k<<<128, 448, 0, stream>>>(fused, cin[35], cin[36], cin[37], cin[38], cin[39], cin[40],
                                  d_out, (const u16*)d_in[21]);
}